// Round 14
// baseline (100.375 us; speedup 1.0000x reference)
//
#include <hip/hip_runtime.h>
#include <hip/hip_bf16.h>
#include <math.h>

typedef __attribute__((ext_vector_type(8))) short bf16x8;
typedef __attribute__((ext_vector_type(4))) float f32x4;
typedef unsigned long long u64;

#define NSAMP  128000
#define TFR    501
#define NFR    32064       // 64*501 frames per signal
#define FPOW   257
#define NF     257
#define B_SZ   64
#define CHUNKT 32
#define NCH    16
#define EPS_F  1.1920928955078125e-07f

#define SEG    16640       // 64*256 + 256 samples per 64-frame chunk
#define SEGB   33280       // SEG * 2 bytes (bf16)
#define BPHB   32768       // one K=32 phase of basis: 512 cols = 32 KB

// ---- basis, layout [ph(16)][colgrp(32)][lane(64)][8 bf16] ---------------
// col = colgrp*16 + (lane&15); k = ph*32 + (lane>>4)*8 + j.
// col semantic: (bin>>4)*32 + isIm*16 + (bin&15); col 16 = Nyquist basis.
// Wave reading frag (ph,colgrp): lane l -> base + l*16B, fully coalesced.
__global__ __launch_bounds__(256)
void build_basis(unsigned short* __restrict__ Bt) {
    int col = blockIdx.x;
    int g = col >> 5, o = col & 15;
    int isIm = (col >> 4) & 1;
    int bin = g * 16 + o;
    for (int k = threadIdx.x; k < 512; k += 256) {
        float w = sinf((float)k * (float)(M_PI / 512.0));   // sqrt-hann
        float v;
        if (col == 16) {
            v = w * ((k & 1) ? -1.f : 1.f);
        } else {
            int mm = (bin * k) & 511;
            float th = (float)mm * (float)(2.0 * M_PI / 512.0);
            v = w * (isIm ? -sinf(th) : cosf(th));
        }
        __hip_bfloat16 h = __float2bfloat16(v);
        int ph = k >> 5, kq = (k >> 3) & 3, j = k & 7;
        size_t idx = (((size_t)ph * 32 + (col >> 4)) * 64
                      + kq * 16 + (col & 15)) * 8 + j;
        Bt[idx] = *reinterpret_cast<unsigned short*>(&h);
    }
}

// ---- MFMA DFT GEMM v14: K=64 rounds, ping-pong B regs, barrier-free -----
// grid (8 mchunk, 64 b, 2 s) = 1024 blocks, block 512 (8 waves, 1M x 8N).
// Wave tile 64x64 (acc[4][4] = 64 acc regs). A: 33KB swizzled LDS window.
// B: L2-resident basis -> 8 coalesced reg-loads per K=64 round, prefetched
// one full round ahead (2x unrolled loop, named B0/B1, no copies).
__global__ __launch_bounds__(512)
void dft_gemm(const float* __restrict__ sig,
              const float* __restrict__ intf,
              const unsigned short* __restrict__ Bt,
              _Float16* __restrict__ powo)
{
    __shared__ char As[SEGB];

    const int mchunk = blockIdx.x, b = blockIdx.y, s = blockIdx.z;
    const int tid = threadIdx.x, lane = tid & 63, wn = tid >> 6;  // 8 waves
    const int lq = lane >> 4, ll = lane & 15;
    const float* x = (s == 0 ? intf : sig) + (size_t)b * NSAMP;
    const int tbase = mchunk * 16384 - 256;

    // ---- A staging: contiguous segment, float4, bf16, addr-XOR swizzle ----
    {
        const int jlo = (tbase < 0) ? -tbase : 0;
        const int jhi = (tbase + SEG > NSAMP) ? (NSAMP - tbase) : SEG;
        for (int i = tid; i < SEG / 4; i += 512) {
            int j = i * 4;
            float f0, f1, f2, f3;
            if (j >= jlo && j + 4 <= jhi) {
                float4 v = *(const float4*)(x + tbase + j);
                f0 = v.x; f1 = v.y; f2 = v.z; f3 = v.w;
            } else {
                int p0 = tbase + j;
                int pp[4];
                #pragma unroll
                for (int e = 0; e < 4; ++e) {
                    int p = p0 + e;
                    if (p < 0) p = -p;
                    if (p >= NSAMP) p = 2 * NSAMP - 2 - p;
                    pp[e] = p;
                }
                f0 = x[pp[0]]; f1 = x[pp[1]]; f2 = x[pp[2]]; f3 = x[pp[3]];
            }
            unsigned short h[4];
            __hip_bfloat16 t0 = __float2bfloat16(f0); h[0] = *(unsigned short*)&t0;
            __hip_bfloat16 t1 = __float2bfloat16(f1); h[1] = *(unsigned short*)&t1;
            __hip_bfloat16 t2 = __float2bfloat16(f2); h[2] = *(unsigned short*)&t2;
            __hip_bfloat16 t3 = __float2bfloat16(f3); h[3] = *(unsigned short*)&t3;
            u64 pk = (u64)h[0] | ((u64)h[1] << 16) |
                     ((u64)h[2] << 32) | ((u64)h[3] << 48);
            int a = i * 8;
            a ^= ((a >> 9) & 7) << 4;
            *(u64*)(As + a) = pk;
        }
    }
    __syncthreads();    // the ONLY barrier: A ready; K-loop free-runs

    f32x4 acc[4][4];
    #pragma unroll
    for (int i = 0; i < 4; ++i)
        #pragma unroll
        for (int j = 0; j < 4; ++j) acc[i][j] = 0;

    // per-lane byte base into basis for this wave's 4 col-groups
    const char* bb = (const char*)Bt + (size_t)(wn * 4 * 64 + lane) * 16;

    bf16x8 B0[8], B1[8];

    auto loadR = [&](int r, bf16x8 (&dst)[8]) {   // one K=64 round = 2 phases
        #pragma unroll
        for (int h = 0; h < 2; ++h) {
            const char* bp = bb + (size_t)(2 * r + h) * BPHB;
            #pragma unroll
            for (int nf = 0; nf < 4; ++nf)
                dst[h * 4 + nf] = *(const bf16x8*)(bp + nf * 1024);
        }
    };

    auto doRound = [&](int r, bf16x8 (&cur)[8]) {
        bf16x8 af[2][4];
        #pragma unroll
        for (int h = 0; h < 2; ++h)
            #pragma unroll
            for (int mf = 0; mf < 4; ++mf) {
                int a = (mf * 16 + ll) * 512 + (2 * r + h) * 64 + lq * 16;
                a ^= ((a >> 9) & 7) << 4;
                af[h][mf] = *(const bf16x8*)(As + a);
            }
        __builtin_amdgcn_s_setprio(1);
        #pragma unroll
        for (int h = 0; h < 2; ++h)
            #pragma unroll
            for (int mf = 0; mf < 4; ++mf)
                #pragma unroll
                for (int nf = 0; nf < 4; ++nf)
                    acc[mf][nf] = __builtin_amdgcn_mfma_f32_16x16x32_bf16(
                        af[h][mf], cur[h * 4 + nf], acc[mf][nf], 0, 0, 0);
        __builtin_amdgcn_s_setprio(0);
    };

    loadR(0, B0);
    #pragma unroll 1
    for (int rr = 0; rr < 4; ++rr) {
        loadR(rr * 2 + 1, B1);              // prefetch odd round
        doRound(rr * 2, B0);
        if (rr < 3) loadR(rr * 2 + 2, B0);  // prefetch next even round
        doRound(rr * 2 + 1, B1);
    }

    // ---- epilogue: power = re^2 + im^2, fp16 stores ----
    const size_t rowbase = ((size_t)(s * 64 + b)) * TFR;
    #pragma unroll
    for (int mf = 0; mf < 4; ++mf) {
        #pragma unroll
        for (int p = 0; p < 2; ++p) {
            f32x4 re = acc[mf][2 * p], im = acc[mf][2 * p + 1];
            int gbin = wn * 2 + p;
            int bin = gbin * 16 + ll;
            bool nyq = (gbin == 0) && (ll == 0);
            #pragma unroll
            for (int j = 0; j < 4; ++j) {
                int rl = mchunk * 64 + mf * 16 + lq * 4 + j;
                if (rl < TFR) {
                    float pr = re[j] * re[j];
                    float pi = im[j] * im[j];
                    _Float16* po = powo + (rowbase + rl) * FPOW;
                    po[bin] = (_Float16)(nyq ? pr : (pr + pi));
                    if (nyq) po[256] = (_Float16)pi;
                }
            }
        }
    }
}

// ---- warm-up: batched loads then fmaf chain (fp16 planes) ---------------
template<int W>
__device__ __forceinline__ float warm_sum(const _Float16* __restrict__ nrow,
                                          int ts, float alpha, float oma) {
    float q[W + 1];
    #pragma unroll
    for (int i = 0; i <= W; ++i) q[i] = (float)nrow[(size_t)(ts + i) * FPOW];
    float v = q[0];
    #pragma unroll
    for (int i = 1; i <= W; ++i) v = fmaf(alpha, v, oma * q[i]);
    return v;
}

// ---- chunked IIR scan + SPP + MSE, fp16 power planes --------------------
__global__ __launch_bounds__(256, 4)
void spp_loss_kernel(const _Float16* __restrict__ noiseP,
                     const _Float16* __restrict__ noisyP,
                     const float* __restrict__ est,
                     float* __restrict__ out,
                     float alpha)
{
    const double XI = 31.622776601683793;
    const float RATIO = (float)(1.0 + XI);
    const float COEF  = (float)(XI / (1.0 + XI));
    const float INVN  = (float)(1.0 / ((double)B_SZ * NF * TFR));

    int tid = blockIdx.x * blockDim.x + threadIdx.x;
    int f   = tid % NF;
    int rem = tid / NF;
    int c   = rem & (NCH - 1);
    int b   = rem >> 4;

    float local = 0.f;
    if (b < B_SZ) {
        const int t0   = c * CHUNKT;
        const int tend = min(TFR, t0 + CHUNKT);
        const _Float16* nrow = noiseP + (size_t)b * TFR * FPOW + f;
        const _Float16* yrow = noisyP + (size_t)b * TFR * FPOW + f;
        const float* erow = est + ((size_t)b * NF + f) * TFR;
        const float oma = 1.f - alpha;

        float v;
        if (t0 == 0)            v = (float)nrow[0];
        else if (t0 == CHUNKT)  v = warm_sum<CHUNKT>(nrow, 0, alpha, oma);
        else                    v = warm_sum<48>(nrow, t0 - 48, alpha, oma);

        {
            float np = (float)yrow[(size_t)t0 * FPOW];
            float e0 = erow[t0];
            float expo = -np / (v + EPS_F) * COEF;
            float spp  = 1.f / fmaf(RATIO, __expf(expo), 1.f);
            float d = e0 - spp;
            local = fmaf(d, d, local);
        }
        #pragma unroll
        for (int h = 0; h < 2; ++h) {
            float qn[16], qy[16], qe[16];
            #pragma unroll
            for (int i = 0; i < 16; ++i) {
                int t = min(t0 + h * 16 + i + 1, TFR - 1);
                qn[i] = (float)nrow[(size_t)t * FPOW];
                qy[i] = (float)yrow[(size_t)t * FPOW];
                qe[i] = erow[t];
            }
            #pragma unroll
            for (int i = 0; i < 16; ++i) {
                int t = t0 + h * 16 + i + 1;
                v = fmaf(alpha, v, oma * qn[i]);
                if (t < tend) {
                    float expo = -qy[i] / (v + EPS_F) * COEF;
                    float spp  = 1.f / fmaf(RATIO, __expf(expo), 1.f);
                    float d = qe[i] - spp;
                    local = fmaf(d, d, local);
                }
            }
        }
    }

    for (int off = 32; off > 0; off >>= 1)
        local += __shfl_down(local, off);
    __shared__ float wsum[4];
    if ((threadIdx.x & 63) == 0) wsum[threadIdx.x >> 6] = local;
    __syncthreads();
    if (threadIdx.x == 0) {
        float ssum = (wsum[0] + wsum[1]) + (wsum[2] + wsum[3]);
        atomicAdd(out, ssum * INVN);
    }
}

extern "C" void kernel_launch(void* const* d_in, const int* in_sizes, int n_in,
                              void* d_out, int out_size, void* d_ws, size_t ws_size,
                              hipStream_t stream) {
    const float* est  = (const float*)d_in[0];   // spp_estimate (B,1,F,T)
    const float* sig  = (const float*)d_in[1];   // input_sig    (B,1,N)
    const float* intf = (const float*)d_in[2];   // interference (B,1,N)

    unsigned short* Bt = (unsigned short*)d_ws;                 // 512 KB basis
    _Float16* powp = (_Float16*)((char*)d_ws + (size_t)512 * 1024);

    hipLaunchKernelGGL(build_basis, dim3(512), dim3(256), 0, stream, Bt);
    hipMemsetAsync(d_out, 0, sizeof(float), stream);

    dim3 gG(8, 64, 2);
    hipLaunchKernelGGL(dft_gemm, gG, dim3(512), 0, stream,
                       sig, intf, Bt, powp);

    const double alpha_d = exp(-((double)256) / (16000.0 * 0.072));
    const _Float16* noiseP = powp;                          // s=0: interference
    const _Float16* noisyP = powp + (size_t)NFR * FPOW;     // s=1: input_sig
    dim3 gB((B_SZ * NCH * NF + 255) / 256);
    hipLaunchKernelGGL(spp_loss_kernel, gB, dim3(256), 0, stream,
                       noiseP, noisyP, est, (float*)d_out, (float)alpha_d);
}

// Round 15
// 96.914 us; speedup vs baseline: 1.0357x; 1.0357x over previous
//
#include <hip/hip_runtime.h>
#include <hip/hip_bf16.h>
#include <math.h>

typedef __attribute__((ext_vector_type(8))) short bf16x8;
typedef __attribute__((ext_vector_type(4))) float f32x4;
typedef unsigned long long u64;

#define NSAMP  128000
#define TFR    501
#define NFR    32064       // 64*501 frames per signal
#define FPOW   257
#define NF     257
#define B_SZ   64
#define CHUNKT 32
#define NCH    16
#define EPS_F  1.1920928955078125e-07f

#define SEG    16640       // 64*256 + 256 samples per 64-frame chunk
#define SEGB   33280       // SEG * 2 bytes (bf16)
#define BPHB   32768       // one K=32 phase of basis: 512 cols = 32 KB

// ---- basis, layout [ph(16)][colgrp(32)][lane(64)][8 bf16] ---------------
// col = colgrp*16 + (lane&15); k = ph*32 + (lane>>4)*8 + j.
// col semantic: (bin>>4)*32 + isIm*16 + (bin&15); col 16 = Nyquist basis.
// Wave reading frag (ph,colgrp): lane l -> base + l*16B, fully coalesced.
__global__ __launch_bounds__(256)
void build_basis(unsigned short* __restrict__ Bt) {
    int col = blockIdx.x;
    int g = col >> 5, o = col & 15;
    int isIm = (col >> 4) & 1;
    int bin = g * 16 + o;
    for (int k = threadIdx.x; k < 512; k += 256) {
        float w = sinf((float)k * (float)(M_PI / 512.0));   // sqrt-hann
        float v;
        if (col == 16) {
            v = w * ((k & 1) ? -1.f : 1.f);
        } else {
            int mm = (bin * k) & 511;
            float th = (float)mm * (float)(2.0 * M_PI / 512.0);
            v = w * (isIm ? -sinf(th) : cosf(th));
        }
        __hip_bfloat16 h = __float2bfloat16(v);
        int ph = k >> 5, kq = (k >> 3) & 3, j = k & 7;
        size_t idx = (((size_t)ph * 32 + (col >> 4)) * 64
                      + kq * 16 + (col & 15)) * 8 + j;
        Bt[idx] = *reinterpret_cast<unsigned short*>(&h);
    }
}

// ---- MFMA DFT GEMM v15: r13 structure, copy-free B ping-pong ------------
// grid (8 mchunk, 64 b, 2 s) = 1024 blocks, block 512 (8 waves, 1M x 8N).
// Wave tile 64x64 (acc[4][4] = 64 acc regs). A: 33KB swizzled LDS window.
// B: L2-resident basis -> 4 coalesced reg-loads/phase, prefetch distance 1,
// 2x-unrolled loop with named B0/B1 (no register rotation movs).
__global__ __launch_bounds__(512)
void dft_gemm(const float* __restrict__ sig,
              const float* __restrict__ intf,
              const unsigned short* __restrict__ Bt,
              _Float16* __restrict__ powo)
{
    __shared__ char As[SEGB];

    const int mchunk = blockIdx.x, b = blockIdx.y, s = blockIdx.z;
    const int tid = threadIdx.x, lane = tid & 63, wn = tid >> 6;  // 8 waves
    const int lq = lane >> 4, ll = lane & 15;
    const float* x = (s == 0 ? intf : sig) + (size_t)b * NSAMP;
    const int tbase = mchunk * 16384 - 256;

    // ---- A staging: contiguous segment, float4, bf16, addr-XOR swizzle ----
    {
        const int jlo = (tbase < 0) ? -tbase : 0;
        const int jhi = (tbase + SEG > NSAMP) ? (NSAMP - tbase) : SEG;
        for (int i = tid; i < SEG / 4; i += 512) {
            int j = i * 4;
            float f0, f1, f2, f3;
            if (j >= jlo && j + 4 <= jhi) {
                float4 v = *(const float4*)(x + tbase + j);
                f0 = v.x; f1 = v.y; f2 = v.z; f3 = v.w;
            } else {
                int p0 = tbase + j;
                int pp[4];
                #pragma unroll
                for (int e = 0; e < 4; ++e) {
                    int p = p0 + e;
                    if (p < 0) p = -p;
                    if (p >= NSAMP) p = 2 * NSAMP - 2 - p;
                    pp[e] = p;
                }
                f0 = x[pp[0]]; f1 = x[pp[1]]; f2 = x[pp[2]]; f3 = x[pp[3]];
            }
            unsigned short h[4];
            __hip_bfloat16 t0 = __float2bfloat16(f0); h[0] = *(unsigned short*)&t0;
            __hip_bfloat16 t1 = __float2bfloat16(f1); h[1] = *(unsigned short*)&t1;
            __hip_bfloat16 t2 = __float2bfloat16(f2); h[2] = *(unsigned short*)&t2;
            __hip_bfloat16 t3 = __float2bfloat16(f3); h[3] = *(unsigned short*)&t3;
            u64 pk = (u64)h[0] | ((u64)h[1] << 16) |
                     ((u64)h[2] << 32) | ((u64)h[3] << 48);
            int a = i * 8;
            a ^= ((a >> 9) & 7) << 4;
            *(u64*)(As + a) = pk;
        }
    }
    __syncthreads();    // the ONLY barrier: A ready; K-loop free-runs

    f32x4 acc[4][4];
    #pragma unroll
    for (int i = 0; i < 4; ++i)
        #pragma unroll
        for (int j = 0; j < 4; ++j) acc[i][j] = 0;

    // per-lane byte base into basis for this wave's 4 col-groups
    const char* bb = (const char*)Bt + (size_t)(wn * 4 * 64 + lane) * 16;

    bf16x8 B0[4], B1[4];

    auto loadPh = [&](int ph, bf16x8 (&dst)[4]) {
        const char* bp = bb + (size_t)ph * BPHB;
        #pragma unroll
        for (int nf = 0; nf < 4; ++nf)
            dst[nf] = *(const bf16x8*)(bp + nf * 1024);
    };

    auto doPhase = [&](int ph, bf16x8 (&cur)[4]) {
        bf16x8 af[4];
        #pragma unroll
        for (int mf = 0; mf < 4; ++mf) {
            int a = (mf * 16 + ll) * 512 + ph * 64 + lq * 16;
            a ^= ((a >> 9) & 7) << 4;
            af[mf] = *(const bf16x8*)(As + a);
        }
        __builtin_amdgcn_s_setprio(1);
        #pragma unroll
        for (int mf = 0; mf < 4; ++mf)
            #pragma unroll
            for (int nf = 0; nf < 4; ++nf)
                acc[mf][nf] = __builtin_amdgcn_mfma_f32_16x16x32_bf16(
                    af[mf], cur[nf], acc[mf][nf], 0, 0, 0);
        __builtin_amdgcn_s_setprio(0);
    };

    loadPh(0, B0);
    #pragma unroll 1
    for (int pp2 = 0; pp2 < 8; ++pp2) {
        const int ph = pp2 * 2;
        loadPh(ph + 1, B1);                 // prefetch odd phase
        doPhase(ph, B0);                    // compute even phase
        if (pp2 < 7) loadPh(ph + 2, B0);    // prefetch next even phase
        doPhase(ph + 1, B1);                // compute odd phase
    }

    // ---- epilogue: power = re^2 + im^2, fp16 stores ----
    const size_t rowbase = ((size_t)(s * 64 + b)) * TFR;
    #pragma unroll
    for (int mf = 0; mf < 4; ++mf) {
        #pragma unroll
        for (int p = 0; p < 2; ++p) {
            f32x4 re = acc[mf][2 * p], im = acc[mf][2 * p + 1];
            int gbin = wn * 2 + p;
            int bin = gbin * 16 + ll;
            bool nyq = (gbin == 0) && (ll == 0);
            #pragma unroll
            for (int j = 0; j < 4; ++j) {
                int rl = mchunk * 64 + mf * 16 + lq * 4 + j;
                if (rl < TFR) {
                    float pr = re[j] * re[j];
                    float pi = im[j] * im[j];
                    _Float16* po = powo + (rowbase + rl) * FPOW;
                    po[bin] = (_Float16)(nyq ? pr : (pr + pi));
                    if (nyq) po[256] = (_Float16)pi;
                }
            }
        }
    }
}

// ---- warm-up: batched loads then fmaf chain (fp16 planes) ---------------
template<int W>
__device__ __forceinline__ float warm_sum(const _Float16* __restrict__ nrow,
                                          int ts, float alpha, float oma) {
    float q[W + 1];
    #pragma unroll
    for (int i = 0; i <= W; ++i) q[i] = (float)nrow[(size_t)(ts + i) * FPOW];
    float v = q[0];
    #pragma unroll
    for (int i = 1; i <= W; ++i) v = fmaf(alpha, v, oma * q[i]);
    return v;
}

// ---- chunked IIR scan + SPP + MSE, fp16 power planes --------------------
__global__ __launch_bounds__(256, 4)
void spp_loss_kernel(const _Float16* __restrict__ noiseP,
                     const _Float16* __restrict__ noisyP,
                     const float* __restrict__ est,
                     float* __restrict__ out,
                     float alpha)
{
    const double XI = 31.622776601683793;
    const float RATIO = (float)(1.0 + XI);
    const float COEF  = (float)(XI / (1.0 + XI));
    const float INVN  = (float)(1.0 / ((double)B_SZ * NF * TFR));

    int tid = blockIdx.x * blockDim.x + threadIdx.x;
    int f   = tid % NF;
    int rem = tid / NF;
    int c   = rem & (NCH - 1);
    int b   = rem >> 4;

    float local = 0.f;
    if (b < B_SZ) {
        const int t0   = c * CHUNKT;
        const int tend = min(TFR, t0 + CHUNKT);
        const _Float16* nrow = noiseP + (size_t)b * TFR * FPOW + f;
        const _Float16* yrow = noisyP + (size_t)b * TFR * FPOW + f;
        const float* erow = est + ((size_t)b * NF + f) * TFR;
        const float oma = 1.f - alpha;

        float v;
        if (t0 == 0)            v = (float)nrow[0];
        else if (t0 == CHUNKT)  v = warm_sum<CHUNKT>(nrow, 0, alpha, oma);
        else                    v = warm_sum<48>(nrow, t0 - 48, alpha, oma);

        {
            float np = (float)yrow[(size_t)t0 * FPOW];
            float e0 = erow[t0];
            float expo = -np / (v + EPS_F) * COEF;
            float spp  = 1.f / fmaf(RATIO, __expf(expo), 1.f);
            float d = e0 - spp;
            local = fmaf(d, d, local);
        }
        #pragma unroll
        for (int h = 0; h < 2; ++h) {
            float qn[16], qy[16], qe[16];
            #pragma unroll
            for (int i = 0; i < 16; ++i) {
                int t = min(t0 + h * 16 + i + 1, TFR - 1);
                qn[i] = (float)nrow[(size_t)t * FPOW];
                qy[i] = (float)yrow[(size_t)t * FPOW];
                qe[i] = erow[t];
            }
            #pragma unroll
            for (int i = 0; i < 16; ++i) {
                int t = t0 + h * 16 + i + 1;
                v = fmaf(alpha, v, oma * qn[i]);
                if (t < tend) {
                    float expo = -qy[i] / (v + EPS_F) * COEF;
                    float spp  = 1.f / fmaf(RATIO, __expf(expo), 1.f);
                    float d = qe[i] - spp;
                    local = fmaf(d, d, local);
                }
            }
        }
    }

    for (int off = 32; off > 0; off >>= 1)
        local += __shfl_down(local, off);
    __shared__ float wsum[4];
    if ((threadIdx.x & 63) == 0) wsum[threadIdx.x >> 6] = local;
    __syncthreads();
    if (threadIdx.x == 0) {
        float ssum = (wsum[0] + wsum[1]) + (wsum[2] + wsum[3]);
        atomicAdd(out, ssum * INVN);
    }
}

extern "C" void kernel_launch(void* const* d_in, const int* in_sizes, int n_in,
                              void* d_out, int out_size, void* d_ws, size_t ws_size,
                              hipStream_t stream) {
    const float* est  = (const float*)d_in[0];   // spp_estimate (B,1,F,T)
    const float* sig  = (const float*)d_in[1];   // input_sig    (B,1,N)
    const float* intf = (const float*)d_in[2];   // interference (B,1,N)

    unsigned short* Bt = (unsigned short*)d_ws;                 // 512 KB basis
    _Float16* powp = (_Float16*)((char*)d_ws + (size_t)512 * 1024);

    hipLaunchKernelGGL(build_basis, dim3(512), dim3(256), 0, stream, Bt);
    hipMemsetAsync(d_out, 0, sizeof(float), stream);

    dim3 gG(8, 64, 2);
    hipLaunchKernelGGL(dft_gemm, gG, dim3(512), 0, stream,
                       sig, intf, Bt, powp);

    const double alpha_d = exp(-((double)256) / (16000.0 * 0.072));
    const _Float16* noiseP = powp;                          // s=0: interference
    const _Float16* noisyP = powp + (size_t)NFR * FPOW;     // s=1: input_sig
    dim3 gB((B_SZ * NCH * NF + 255) / 256);
    hipLaunchKernelGGL(spp_loss_kernel, gB, dim3(256), 0, stream,
                       noiseP, noisyP, est, (float*)d_out, (float)alpha_d);
}

// Round 16
// 90.078 us; speedup vs baseline: 1.1143x; 1.0759x over previous
//
#include <hip/hip_runtime.h>
#include <hip/hip_bf16.h>
#include <math.h>

typedef __attribute__((ext_vector_type(8))) short bf16x8;
typedef __attribute__((ext_vector_type(4))) float f32x4;
typedef __attribute__((ext_vector_type(8))) _Float16 h8;
typedef unsigned long long u64;

#define NSAMP  128000
#define TFR    501
#define TP     512         // padded t-stride of power planes
#define FPOW   257
#define NF     257
#define B_SZ   64
#define CHUNKT 32
#define NCH    16
#define EPS_F  1.1920928955078125e-07f

#define SEG    16640       // 64*256 + 256 samples per 64-frame chunk
#define SEGB   33280       // SEG * 2 bytes (bf16)
#define BPHB   32768       // one K=32 phase of basis: 512 cols = 32 KB

// ---- basis, layout [ph(16)][colgrp(32)][lane(64)][8 bf16] ---------------
// col = colgrp*16 + (lane&15); k = ph*32 + (lane>>4)*8 + j.
// col semantic: (bin>>4)*32 + isIm*16 + (bin&15); col 16 = Nyquist basis.
__global__ __launch_bounds__(256)
void build_basis(unsigned short* __restrict__ Bt) {
    int col = blockIdx.x;
    int g = col >> 5, o = col & 15;
    int isIm = (col >> 4) & 1;
    int bin = g * 16 + o;
    for (int k = threadIdx.x; k < 512; k += 256) {
        float w = sinf((float)k * (float)(M_PI / 512.0));   // sqrt-hann
        float v;
        if (col == 16) {
            v = w * ((k & 1) ? -1.f : 1.f);
        } else {
            int mm = (bin * k) & 511;
            float th = (float)mm * (float)(2.0 * M_PI / 512.0);
            v = w * (isIm ? -sinf(th) : cosf(th));
        }
        __hip_bfloat16 h = __float2bfloat16(v);
        int ph = k >> 5, kq = (k >> 3) & 3, j = k & 7;
        size_t idx = (((size_t)ph * 32 + (col >> 4)) * 64
                      + kq * 16 + (col & 15)) * 8 + j;
        Bt[idx] = *reinterpret_cast<unsigned short*>(&h);
    }
}

// ---- MFMA DFT GEMM v16: r15 K-loop, t-major fp16 power output -----------
// grid (8 mchunk, 64 b, 2 s) = 1024 blocks, block 512 (8 waves, 1M x 8N).
// Output: pow[sb][bin][t] fp16, t padded to 512 (pad never read by spp).
// Each lane packs 4 consecutive-t fp16 into one u64 store.
__global__ __launch_bounds__(512)
void dft_gemm(const float* __restrict__ sig,
              const float* __restrict__ intf,
              const unsigned short* __restrict__ Bt,
              _Float16* __restrict__ powo)
{
    __shared__ char As[SEGB];

    const int mchunk = blockIdx.x, b = blockIdx.y, s = blockIdx.z;
    const int tid = threadIdx.x, lane = tid & 63, wn = tid >> 6;  // 8 waves
    const int lq = lane >> 4, ll = lane & 15;
    const float* x = (s == 0 ? intf : sig) + (size_t)b * NSAMP;
    const int tbase = mchunk * 16384 - 256;

    // ---- A staging: contiguous segment, float4, bf16, addr-XOR swizzle ----
    {
        const int jlo = (tbase < 0) ? -tbase : 0;
        const int jhi = (tbase + SEG > NSAMP) ? (NSAMP - tbase) : SEG;
        for (int i = tid; i < SEG / 4; i += 512) {
            int j = i * 4;
            float f0, f1, f2, f3;
            if (j >= jlo && j + 4 <= jhi) {
                float4 v = *(const float4*)(x + tbase + j);
                f0 = v.x; f1 = v.y; f2 = v.z; f3 = v.w;
            } else {
                int p0 = tbase + j;
                int pp[4];
                #pragma unroll
                for (int e = 0; e < 4; ++e) {
                    int p = p0 + e;
                    if (p < 0) p = -p;
                    if (p >= NSAMP) p = 2 * NSAMP - 2 - p;
                    pp[e] = p;
                }
                f0 = x[pp[0]]; f1 = x[pp[1]]; f2 = x[pp[2]]; f3 = x[pp[3]];
            }
            unsigned short h[4];
            __hip_bfloat16 t0 = __float2bfloat16(f0); h[0] = *(unsigned short*)&t0;
            __hip_bfloat16 t1 = __float2bfloat16(f1); h[1] = *(unsigned short*)&t1;
            __hip_bfloat16 t2 = __float2bfloat16(f2); h[2] = *(unsigned short*)&t2;
            __hip_bfloat16 t3 = __float2bfloat16(f3); h[3] = *(unsigned short*)&t3;
            u64 pk = (u64)h[0] | ((u64)h[1] << 16) |
                     ((u64)h[2] << 32) | ((u64)h[3] << 48);
            int a = i * 8;
            a ^= ((a >> 9) & 7) << 4;
            *(u64*)(As + a) = pk;
        }
    }
    __syncthreads();    // the ONLY barrier: A ready; K-loop free-runs

    f32x4 acc[4][4];
    #pragma unroll
    for (int i = 0; i < 4; ++i)
        #pragma unroll
        for (int j = 0; j < 4; ++j) acc[i][j] = 0;

    // per-lane byte base into basis for this wave's 4 col-groups
    const char* bb = (const char*)Bt + (size_t)(wn * 4 * 64 + lane) * 16;

    bf16x8 B0[4], B1[4];

    auto loadPh = [&](int ph, bf16x8 (&dst)[4]) {
        const char* bp = bb + (size_t)ph * BPHB;
        #pragma unroll
        for (int nf = 0; nf < 4; ++nf)
            dst[nf] = *(const bf16x8*)(bp + nf * 1024);
    };

    auto doPhase = [&](int ph, bf16x8 (&cur)[4]) {
        bf16x8 af[4];
        #pragma unroll
        for (int mf = 0; mf < 4; ++mf) {
            int a = (mf * 16 + ll) * 512 + ph * 64 + lq * 16;
            a ^= ((a >> 9) & 7) << 4;
            af[mf] = *(const bf16x8*)(As + a);
        }
        __builtin_amdgcn_s_setprio(1);
        #pragma unroll
        for (int mf = 0; mf < 4; ++mf)
            #pragma unroll
            for (int nf = 0; nf < 4; ++nf)
                acc[mf][nf] = __builtin_amdgcn_mfma_f32_16x16x32_bf16(
                    af[mf], cur[nf], acc[mf][nf], 0, 0, 0);
        __builtin_amdgcn_s_setprio(0);
    };

    loadPh(0, B0);
    #pragma unroll 1
    for (int pp2 = 0; pp2 < 8; ++pp2) {
        const int ph = pp2 * 2;
        loadPh(ph + 1, B1);                 // prefetch odd phase
        doPhase(ph, B0);                    // compute even phase
        if (pp2 < 7) loadPh(ph + 2, B0);    // prefetch next even phase
        doPhase(ph + 1, B1);                // compute odd phase
    }

    // ---- epilogue: power = re^2 + im^2, t-major fp16, packed u64 stores ----
    const int sb = s * 64 + b;
    _Float16* pbase = powo + (size_t)sb * FPOW * TP;
    #pragma unroll
    for (int mf = 0; mf < 4; ++mf) {
        const int rl0 = mchunk * 64 + mf * 16 + lq * 4;
        #pragma unroll
        for (int p = 0; p < 2; ++p) {
            f32x4 re = acc[mf][2 * p], im = acc[mf][2 * p + 1];
            int gbin = wn * 2 + p;
            int bin = gbin * 16 + ll;
            bool nyq = (gbin == 0) && (ll == 0);
            unsigned short hp[4], hn[4];
            #pragma unroll
            for (int j = 0; j < 4; ++j) {
                float pr = re[j] * re[j];
                float pi = im[j] * im[j];
                _Float16 hv = (_Float16)(nyq ? pr : (pr + pi));
                hp[j] = *(unsigned short*)&hv;
                _Float16 hw = (_Float16)pi;
                hn[j] = *(unsigned short*)&hw;
            }
            u64 pk = (u64)hp[0] | ((u64)hp[1] << 16) |
                     ((u64)hp[2] << 32) | ((u64)hp[3] << 48);
            *(u64*)(pbase + (size_t)bin * TP + rl0) = pk;
            if (nyq) {
                u64 pk2 = (u64)hn[0] | ((u64)hn[1] << 16) |
                          ((u64)hn[2] << 32) | ((u64)hn[3] << 48);
                *(u64*)(pbase + (size_t)256 * TP + rl0) = pk2;
            }
        }
    }
}

// ---- warm-up: vectorized fp16 loads, static indexing --------------------
template<int W>
__device__ __forceinline__ float warm_fixed(const _Float16* __restrict__ nrow,
                                            int base, float alpha, float oma) {
    h8 blk[W / 8];
    #pragma unroll
    for (int i = 0; i < W / 8; ++i)
        blk[i] = *(const h8*)(nrow + base + i * 8);
    float v = (float)blk[0][0];
    #pragma unroll
    for (int i = 1; i < W; ++i)
        v = fmaf(alpha, v, oma * (float)blk[i / 8][i % 8]);
    v = fmaf(alpha, v, oma * (float)nrow[base + W]);
    return v;
}

// ---- chunked IIR scan + SPP + MSE, t-major fp16 planes ------------------
__global__ __launch_bounds__(256, 4)
void spp_loss_kernel(const _Float16* __restrict__ noiseP,
                     const _Float16* __restrict__ noisyP,
                     const float* __restrict__ est,
                     float* __restrict__ out,
                     float alpha)
{
    const double XI = 31.622776601683793;
    const float RATIO = (float)(1.0 + XI);
    const float COEF  = (float)(XI / (1.0 + XI));
    const float INVN  = (float)(1.0 / ((double)B_SZ * NF * TFR));

    int tid = blockIdx.x * blockDim.x + threadIdx.x;
    int f   = tid % NF;
    int rem = tid / NF;
    int c   = rem & (NCH - 1);
    int b   = rem >> 4;

    float local = 0.f;
    if (b < B_SZ) {
        const int t0   = c * CHUNKT;
        const int tend = min(TFR, t0 + CHUNKT);
        const _Float16* nrow = noiseP + ((size_t)b * NF + f) * TP;
        const _Float16* yrow = noisyP + ((size_t)b * NF + f) * TP;
        const float* erow = est + ((size_t)b * NF + f) * TFR;
        const float oma = 1.f - alpha;

        float v;
        if (t0 == 0)            v = (float)nrow[0];
        else if (t0 == CHUNKT)  v = warm_fixed<32>(nrow, 0, alpha, oma);
        else                    v = warm_fixed<48>(nrow, t0 - 48, alpha, oma);

        // emit window [t0 .. t0+32]: 4 aligned h8 vectors + 1 scalar each
        h8 wn8[4], wy8[4];
        #pragma unroll
        for (int i = 0; i < 4; ++i) {
            wn8[i] = *(const h8*)(nrow + t0 + i * 8);
            wy8[i] = *(const h8*)(yrow + t0 + i * 8);
        }
        float last_n = (float)nrow[t0 + 32];
        float last_y = (float)yrow[t0 + 32];
        float qe[32];
        #pragma unroll
        for (int i = 0; i < 32; ++i)
            qe[i] = erow[min(t0 + 1 + i, TFR - 1)];

        // emit at t0
        {
            float np = (float)wy8[0][0];
            float e0 = erow[t0];
            float expo = -np / (v + EPS_F) * COEF;
            float spp  = 1.f / fmaf(RATIO, __expf(expo), 1.f);
            float d = e0 - spp;
            local = fmaf(d, d, local);
        }
        // emit t0+1 .. tend-1
        #pragma unroll
        for (int i = 0; i < 32; ++i) {
            int t = t0 + 1 + i;
            float nv = (i < 31) ? (float)wn8[(i + 1) / 8][(i + 1) % 8] : last_n;
            v = fmaf(alpha, v, oma * nv);
            if (t < tend) {
                float yv = (i < 31) ? (float)wy8[(i + 1) / 8][(i + 1) % 8] : last_y;
                float expo = -yv / (v + EPS_F) * COEF;
                float spp  = 1.f / fmaf(RATIO, __expf(expo), 1.f);
                float d = qe[i] - spp;
                local = fmaf(d, d, local);
            }
        }
    }

    for (int off = 32; off > 0; off >>= 1)
        local += __shfl_down(local, off);
    __shared__ float wsum[4];
    if ((threadIdx.x & 63) == 0) wsum[threadIdx.x >> 6] = local;
    __syncthreads();
    if (threadIdx.x == 0) {
        float ssum = (wsum[0] + wsum[1]) + (wsum[2] + wsum[3]);
        atomicAdd(out, ssum * INVN);
    }
}

extern "C" void kernel_launch(void* const* d_in, const int* in_sizes, int n_in,
                              void* d_out, int out_size, void* d_ws, size_t ws_size,
                              hipStream_t stream) {
    const float* est  = (const float*)d_in[0];   // spp_estimate (B,1,F,T)
    const float* sig  = (const float*)d_in[1];   // input_sig    (B,1,N)
    const float* intf = (const float*)d_in[2];   // interference (B,1,N)

    unsigned short* Bt = (unsigned short*)d_ws;                 // 512 KB basis
    _Float16* powp = (_Float16*)((char*)d_ws + (size_t)512 * 1024);

    hipLaunchKernelGGL(build_basis, dim3(512), dim3(256), 0, stream, Bt);
    hipMemsetAsync(d_out, 0, sizeof(float), stream);

    dim3 gG(8, 64, 2);
    hipLaunchKernelGGL(dft_gemm, gG, dim3(512), 0, stream,
                       sig, intf, Bt, powp);

    const double alpha_d = exp(-((double)256) / (16000.0 * 0.072));
    const _Float16* noiseP = powp;                            // sb 0..63
    const _Float16* noisyP = powp + (size_t)B_SZ * FPOW * TP; // sb 64..127
    dim3 gB((B_SZ * NCH * NF + 255) / 256);
    hipLaunchKernelGGL(spp_loss_kernel, gB, dim3(256), 0, stream,
                       noiseP, noisyP, est, (float*)d_out, (float)alpha_d);
}